// Round 3
// baseline (10799.854 us; speedup 1.0000x reference)
//
#include <hip/hip_runtime.h>

#define NV0 30000
#define NE0 90000
#define H0 (2*NE0)      // 180000
#define NV1 (NV0+NE0)   // 120000
#define NE1 (3*NE0)     // 270000
#define H1 (2*NE1)      // 540000
#define DF 32
#define DH 128

typedef unsigned short bf16_t;
typedef unsigned int u32;

__device__ __forceinline__ float bf2f(bf16_t b) { return __uint_as_float(((u32)b) << 16); }
__device__ __forceinline__ bf16_t f2bf(float f) {
  u32 u = __float_as_uint(f);
  return (bf16_t)((u + 0x7fffu + ((u >> 16) & 1u)) >> 16);
}
// dtype-flagged helpers: isf32 is wave-uniform
__device__ __forceinline__ float load_f(const void* p, long i, int isf32) {
  return isf32 ? ((const float*)p)[i] : bf2f(((const bf16_t*)p)[i]);
}
__device__ __forceinline__ void store_out(void* p, long i, float v, int isf32) {
  if (isf32) ((float*)p)[i] = v;
  else ((bf16_t*)p)[i] = f2bf(v);
}

struct F3 { float x, y, z; };
__device__ __forceinline__ F3 mkf3(float x, float y, float z){ F3 r; r.x=x; r.y=y; r.z=z; return r; }
__device__ __forceinline__ F3 f3sub(F3 a, F3 b){ return mkf3(a.x-b.x, a.y-b.y, a.z-b.z); }
__device__ __forceinline__ F3 f3add(F3 a, F3 b){ return mkf3(a.x+b.x, a.y+b.y, a.z+b.z); }
__device__ __forceinline__ float f3dot(F3 a, F3 b){ return a.x*b.x + a.y*b.y + a.z*b.z; }
__device__ __forceinline__ F3 f3crs(F3 a, F3 b){
  return mkf3(a.y*b.z - a.z*b.y, a.z*b.x - a.x*b.z, a.x*b.y - a.y*b.x);
}
__device__ __forceinline__ F3 f3nrm(F3 a){
  float r = rsqrtf(f3dot(a,a));
  return mkf3(a.x*r, a.y*r, a.z*r);
}

// ---- dtype detection: if fv is fp32, the low 16 bits of each word are random
// mantissa bits -> as bf16 they have exponents uniform over 0..255 (~45% > 140).
// If fv is genuinely bf16 N(0,1) data, every exponent is <= ~131. One block.
__global__ __launch_bounds__(256) void detect_kernel(const u32* __restrict__ fvw,
                                                     int* __restrict__ flag) {
  __shared__ int cnt;
  if (threadIdx.x == 0) cnt = 0;
  __syncthreads();
  int c = 0;
  #pragma unroll
  for (int j = 0; j < 2; ++j) {
    u32 w = fvw[threadIdx.x * 2 + j];
    u32 e = (w >> 7) & 0xffu;          // exponent field of low half as bf16
    if (e > 140u) c++;
  }
  if (c) atomicAdd(&cnt, c);
  __syncthreads();
  if (threadIdx.x == 0) *flag = (cnt > 8) ? 1 : 0;
}

// generic float-array staging: src (flagged dtype) -> fp32 dst
__global__ __launch_bounds__(256) void cvt_weights_kernel(const void* __restrict__ src,
                                                          float* __restrict__ dst, int n,
                                                          const int* __restrict__ flag) {
  int t = blockIdx.x * 256 + threadIdx.x;
  if (t >= n) return;
  dst[t] = load_f(src, t, *flag);
}

// W_in (4 x 125 x 128) -> fp32 padded (4 x 128 x 128): rows 0..2 zero
__global__ __launch_bounds__(256) void pad_win_kernel(const void* __restrict__ W_in,
                                                      float* __restrict__ Wp,
                                                      const int* __restrict__ flag) {
  int t = blockIdx.x * 256 + threadIdx.x;
  if (t >= 4 * DH * DH) return;
  int s = t >> 14, r = (t >> 7) & 127, o = t & 127;
  float v = 0.f;
  if (r >= 3) v = load_f(W_in, (long)s * (125 * DH) + (r - 3) * DH + o, *flag);
  Wp[t] = v;
}

// output 0: exact passthrough of fv positions (bit-copy within each dtype)
__global__ __launch_bounds__(256) void cvt_out0_kernel(const void* __restrict__ fv,
                                                       void* __restrict__ out,
                                                       const int* __restrict__ flag) {
  int t = blockIdx.x * 256 + threadIdx.x;
  if (t >= NV0 * 3) return;
  int v = t / 3, c = t - v * 3;
  if (*flag) ((float*)out)[t] = ((const float*)fv)[v * DF + c];
  else ((bf16_t*)out)[t] = ((const bf16_t*)fv)[v * DF + c];
}

// MODE 0: pv pass -> atomicAdd into acc[i0*32+c] + dof[i0]
// MODE 1: pe pass -> atomicAdd 0.5*val into outp[(h/2)*32+c]
// MODE 2: pe pass -> atomicAdd 0.5*val into outp[(h/2)*3+c] (positions only)
// RAW=1: fvin is the raw (flag-dtyped) input tensor; RAW=0: fp32 ws buffer
template<int MODE, int RAW>
__global__ __launch_bounds__(256) void flap_mlp(
    const void* __restrict__ fvin, const int* __restrict__ hfIdx,
    const float* __restrict__ Wp, const float* __restrict__ bi,
    const float* __restrict__ Wh, const float* __restrict__ bh,
    const float* __restrict__ Wo, const float* __restrict__ bo,
    float* __restrict__ outp, float* __restrict__ dof,
    const int* __restrict__ flag)
{
  __shared__ __align__(16) float xs_s[4][DH];
  __shared__ __align__(16) float h1_s[4][DH];
  __shared__ __align__(16) float h2_s[4][DH];
  __shared__ __align__(16) float ob_s[4][DF];
  const int lane = threadIdx.x & 63;
  const int wv = threadIdx.x >> 6;
  const int h = blockIdx.x * 4 + wv;   // grid sized so h always valid
  float* xs = xs_s[wv];
  float* h1 = h1_s[wv];
  float* h2 = h2_s[wv];
  float* ob = ob_s[wv];

  const int i0 = hfIdx[h * 4 + 0];
  const int i1 = hfIdx[h * 4 + 1];
  const int i2 = hfIdx[h * 4 + 2];
  const int i3 = hfIdx[h * 4 + 3];
  const int isf32 = RAW ? *flag : 1;

  // ---- gather: xs = flattened 4x32 features; pos slots rewritten below
  {
    int c = lane & 31;
    int va = (lane < 32) ? i0 : i1;
    int vb = (lane < 32) ? i2 : i3;
    if (RAW) {
      xs[lane]      = load_f(fvin, (long)va * DF + c, isf32);
      xs[lane + 64] = load_f(fvin, (long)vb * DF + c, isf32);
    } else {
      xs[lane]      = ((const float*)fvin)[(long)va * DF + c];
      xs[lane + 64] = ((const float*)fvin)[(long)vb * DF + c];
    }
  }
  __syncthreads();

  // ---- local frame (redundant on all lanes)
  F3 p0 = mkf3(xs[0],  xs[1],  xs[2]);
  F3 p1 = mkf3(xs[32], xs[33], xs[34]);
  F3 p2 = mkf3(xs[64], xs[65], xs[66]);
  F3 p3 = mkf3(xs[96], xs[97], xs[98]);
  F3 e1  = f3sub(p1, p0);
  F3 B1  = f3nrm(e1);
  F3 fn0 = f3nrm(f3crs(e1, f3sub(p2, p0)));
  F3 fn1 = f3nrm(f3crs(f3sub(p0, p1), f3sub(p3, p1)));
  F3 B3  = f3nrm(f3add(fn0, fn1));
  F3 B2  = f3crs(B3, B1);
  F3 d2 = f3sub(p2, p0), d3 = f3sub(p3, p0);
  float q10 = f3dot(e1, B1), q11 = f3dot(e1, B2), q12 = f3dot(e1, B3);
  float q20 = f3dot(d2, B1), q21 = f3dot(d2, B2), q22 = f3dot(d2, B3);
  float q30 = f3dot(d3, B1), q31 = f3dot(d3, B2), q32 = f3dot(d3, B3);
  __syncthreads();
  if (lane < 16) {
    int i = lane >> 2, k = lane & 3;
    if (k < 3) {
      float vk0 = (i == 1) ? q10 : ((i == 2) ? q20 : ((i == 3) ? q30 : 0.f));
      float vk1 = (i == 1) ? q11 : ((i == 2) ? q21 : ((i == 3) ? q31 : 0.f));
      float vk2 = (i == 1) ? q12 : ((i == 2) ? q22 : ((i == 3) ? q32 : 0.f));
      xs[i * 32 + k] = (k == 0) ? vk0 : ((k == 1) ? vk1 : vk2);
    }
  }
  __syncthreads();

  const int o0 = lane * 2;
  // ---- layer 1: h1 = relu(x @ Wp + bi)  (fp32 weights, K=128 padded)
  {
    float a0 = bi[o0], a1 = bi[o0 + 1];
    #pragma unroll 4
    for (int e = 0; e < DH; e += 4) {
      float4 xv = *(const float4*)(xs + e);
      float2 w0 = *(const float2*)(Wp + (e + 0) * DH + o0);
      float2 w1 = *(const float2*)(Wp + (e + 1) * DH + o0);
      float2 w2 = *(const float2*)(Wp + (e + 2) * DH + o0);
      float2 w3 = *(const float2*)(Wp + (e + 3) * DH + o0);
      a0 = fmaf(xv.x, w0.x, a0); a1 = fmaf(xv.x, w0.y, a1);
      a0 = fmaf(xv.y, w1.x, a0); a1 = fmaf(xv.y, w1.y, a1);
      a0 = fmaf(xv.z, w2.x, a0); a1 = fmaf(xv.z, w2.y, a1);
      a0 = fmaf(xv.w, w3.x, a0); a1 = fmaf(xv.w, w3.y, a1);
    }
    h1[o0] = fmaxf(a0, 0.f);
    h1[o0 + 1] = fmaxf(a1, 0.f);
  }
  __syncthreads();
  // ---- layer 2: h2 = relu(h1 @ Wh + bh)
  {
    float a0 = bh[o0], a1 = bh[o0 + 1];
    #pragma unroll 4
    for (int e = 0; e < DH; e += 4) {
      float4 xv = *(const float4*)(h1 + e);
      float2 w0 = *(const float2*)(Wh + (e + 0) * DH + o0);
      float2 w1 = *(const float2*)(Wh + (e + 1) * DH + o0);
      float2 w2 = *(const float2*)(Wh + (e + 2) * DH + o0);
      float2 w3 = *(const float2*)(Wh + (e + 3) * DH + o0);
      a0 = fmaf(xv.x, w0.x, a0); a1 = fmaf(xv.x, w0.y, a1);
      a0 = fmaf(xv.y, w1.x, a0); a1 = fmaf(xv.y, w1.y, a1);
      a0 = fmaf(xv.z, w2.x, a0); a1 = fmaf(xv.z, w2.y, a1);
      a0 = fmaf(xv.w, w3.x, a0); a1 = fmaf(xv.w, w3.y, a1);
    }
    h2[o0] = fmaxf(a0, 0.f);
    h2[o0 + 1] = fmaxf(a1, 0.f);
  }
  __syncthreads();
  // ---- layer 3: out = h2 @ Wo + bo (32 outputs; K halved across lane halves)
  {
    const int oc = lane & 31, hf = lane >> 5;
    float a = hf ? 0.f : bo[oc];
    const int kb = hf * 64;
    #pragma unroll 4
    for (int k = kb; k < kb + 64; k += 4) {
      float4 hv = *(const float4*)(h2 + k);
      a = fmaf(hv.x, Wo[(k + 0) * DF + oc], a);
      a = fmaf(hv.y, Wo[(k + 1) * DF + oc], a);
      a = fmaf(hv.z, Wo[(k + 2) * DF + oc], a);
      a = fmaf(hv.w, Wo[(k + 3) * DF + oc], a);
    }
    a += __shfl_down(a, 32);
    if (lane < 32) ob[oc] = a;
  }
  __syncthreads();

  // ---- local2global + emit
  if (lane < 32) {
    float val;
    if (lane < 3) {
      float c0 = ob[0], c1 = ob[1], c2 = ob[2];
      float w1c = (lane == 0) ? B1.x : ((lane == 1) ? B1.y : B1.z);
      float w2c = (lane == 0) ? B2.x : ((lane == 1) ? B2.y : B2.z);
      float w3c = (lane == 0) ? B3.x : ((lane == 1) ? B3.y : B3.z);
      val = c0 * w1c + c1 * w2c + c2 * w3c;
    } else {
      val = ob[lane];
    }
    if (MODE == 0) {
      atomicAdd(&outp[(size_t)i0 * DF + lane], val);
      if (lane == 0) atomicAdd(&dof[i0], 1.f);
    } else if (MODE == 1) {
      atomicAdd(&outp[(size_t)(h >> 1) * DF + lane], 0.5f * val);
    } else {
      if (lane < 3) atomicAdd(&outp[(size_t)(h >> 1) * 3 + lane], 0.5f * val);
    }
  }
}

// even vertices, IN PLACE: buf = acc/dof, pos += prev_pos; emit positions.
// RAW=1: prev comes from the raw input tensor (flag dtype); else fp32 prevf.
template<int RAW>
__global__ __launch_bounds__(256) void finalize_even_kernel(
    float* buf, const float* __restrict__ dof,
    const void* __restrict__ prevraw, const float* __restrict__ prevf,
    void* __restrict__ out, int outbase, const int* __restrict__ flag, int nV) {
  int t = blockIdx.x * 256 + threadIdx.x;
  if (t >= nV * DF) return;
  int v = t >> 5, c = t & 31;
  float val = buf[t] / fmaxf(dof[v], 1.0f);
  if (c < 3) {
    float pp = RAW ? load_f(prevraw, (long)v * DF + c, *flag) : prevf[(long)v * DF + c];
    val += pp;
    store_out(out, (long)outbase + (long)v * 3 + c, val, *flag);
  }
  buf[t] = val;
}

// odd vertices (level 0), IN PLACE: add Ve, keep 32ch fp32, emit positions
__global__ __launch_bounds__(256) void finalize_odd_full_kernel(
    float* oddbuf, const int* __restrict__ hfIdx,
    const float* fveven, void* __restrict__ out, int outbase,
    const int* __restrict__ flag, int nE, int nVeven) {
  int t = blockIdx.x * 256 + threadIdx.x;
  if (t >= nE * DF) return;
  int e = t >> 5, c = t & 31;
  float val = oddbuf[t];
  if (c < 3) {
    int a0 = hfIdx[(size_t)(2 * e) * 4 + 0];
    int a1 = hfIdx[(size_t)(2 * e) * 4 + 1];
    int b0 = hfIdx[(size_t)(2 * e + 1) * 4 + 0];
    int b1 = hfIdx[(size_t)(2 * e + 1) * 4 + 1];
    val += 0.25f * (fveven[(size_t)a0 * DF + c] + fveven[(size_t)a1 * DF + c] +
                    fveven[(size_t)b0 * DF + c] + fveven[(size_t)b1 * DF + c]);
    store_out(out, (long)outbase + (long)(nVeven + e) * 3 + c, val, *flag);
  }
  oddbuf[t] = val;
}

// odd vertices (level 1, final): positions only
__global__ __launch_bounds__(256) void finalize_odd_pos_kernel(
    const float* __restrict__ odd3, const int* __restrict__ hfIdx,
    const float* __restrict__ fveven, void* __restrict__ out, int outbase,
    const int* __restrict__ flag, int nE, int nVeven) {
  int t = blockIdx.x * 256 + threadIdx.x;
  if (t >= nE * 3) return;
  int e = t / 3, c = t - e * 3;
  int a0 = hfIdx[(size_t)(2 * e) * 4 + 0];
  int a1 = hfIdx[(size_t)(2 * e) * 4 + 1];
  int b0 = hfIdx[(size_t)(2 * e + 1) * 4 + 0];
  int b1 = hfIdx[(size_t)(2 * e + 1) * 4 + 1];
  float val = odd3[t] + 0.25f * (fveven[(size_t)a0 * DF + c] + fveven[(size_t)a1 * DF + c] +
                                 fveven[(size_t)b0 * DF + c] + fveven[(size_t)b1 * DF + c]);
  store_out(out, (long)outbase + (long)(nVeven + e) * 3 + c, val, *flag);
}

extern "C" void kernel_launch(void* const* d_in, const int* in_sizes, int n_in,
                              void* d_out, int out_size, void* d_ws, size_t ws_size,
                              hipStream_t stream) {
  const void* fv    = d_in[0];   // 30000x32 (fp32 or bf16 — auto-detected)
  const void* W_in  = d_in[1];   // 4x125x128
  const void* b_in  = d_in[2];   // 4x128
  const void* W_h   = d_in[3];   // 4x128x128
  const void* b_h   = d_in[4];   // 4x128
  const void* W_out = d_in[5];   // 4x128x32
  const void* b_out = d_in[6];   // 4x32
  const int* hf0 = (const int*)d_in[7];   // 180000x4
  const int* hf1 = (const int*)d_in[8];   // 540000x4
  (void)in_sizes; (void)n_in; (void)out_size;

  // workspace (fp32), ~30.3 MiB
  float* fv1   = (float*)d_ws;            // 3,840,000 (120000x32; even acc in place, odd3 reuse)
  float* fvup2 = fv1   + 3840000;         // 3,840,000 (level-1 acc in place)
  float* dof   = fvup2 + 3840000;         // 120,000
  float* Wpf   = dof   + 120000;          // 65,536 (padded W_in, fp32)
  float* Whf   = Wpf   + 65536;           // 65,536
  float* Wof   = Whf   + 65536;           // 16,384
  float* bif   = Wof   + 16384;           // 512
  float* bhf   = bif   + 512;             // 512
  float* bof   = bhf   + 512;             // 128
  int*   flag  = (int*)(bof + 128);       // 1
  const size_t needed = ((size_t)3840000*2 + 120000 + 65536*2 + 16384 + 512*2 + 128 + 4) * 4;
  if (ws_size < needed) return;  // diagnostic: finite absmax 4.97 + zero output => ws too small

  float* odd_acc0 = fv1 + (size_t)NV0 * DF;  // level-0 odd region (90000x32)

  // ---- dtype detect + staging
  detect_kernel<<<1, 256, 0, stream>>>((const u32*)fv, flag);
  pad_win_kernel<<<(4 * DH * DH + 255) / 256, 256, 0, stream>>>(W_in, Wpf, flag);
  cvt_weights_kernel<<<(65536 + 255) / 256, 256, 0, stream>>>(W_h, Whf, 65536, flag);
  cvt_weights_kernel<<<(16384 + 255) / 256, 256, 0, stream>>>(W_out, Wof, 16384, flag);
  cvt_weights_kernel<<<2, 256, 0, stream>>>(b_in, bif, 512, flag);
  cvt_weights_kernel<<<2, 256, 0, stream>>>(b_h, bhf, 512, flag);
  cvt_weights_kernel<<<1, 256, 0, stream>>>(b_out, bof, 128, flag);
  cvt_out0_kernel<<<(NV0 * 3 + 255) / 256, 256, 0, stream>>>(fv, d_out, flag);

  // ================= level 0 =================
  hipMemsetAsync(fv1, 0, (size_t)NV0 * DF * 4, stream);
  hipMemsetAsync(dof, 0, (size_t)NV0 * 4, stream);
  flap_mlp<0, 1><<<H0 / 4, 256, 0, stream>>>(fv, hf0,
      Wpf + 0 * 16384, bif + 0 * DH, Whf + 0 * 16384, bhf + 0 * DH,
      Wof + 0 * 4096, bof + 0 * DF, fv1, dof, flag);
  finalize_even_kernel<1><<<(NV0 * DF + 255) / 256, 256, 0, stream>>>(
      fv1, dof, fv, nullptr, d_out, 90000, flag, NV0);
  hipMemsetAsync(odd_acc0, 0, (size_t)NE0 * DF * 4, stream);
  flap_mlp<1, 0><<<H0 / 4, 256, 0, stream>>>(fv1, hf0,
      Wpf + 1 * 16384, bif + 1 * DH, Whf + 1 * 16384, bhf + 1 * DH,
      Wof + 1 * 4096, bof + 1 * DF, odd_acc0, nullptr, flag);
  finalize_odd_full_kernel<<<(NE0 * DF + 255) / 256, 256, 0, stream>>>(
      odd_acc0, hf0, fv1, d_out, 90000, flag, NE0, NV0);

  // ================= level 1 =================
  hipMemsetAsync(fvup2, 0, (size_t)NV1 * DF * 4, stream);
  hipMemsetAsync(dof, 0, (size_t)NV1 * 4, stream);
  flap_mlp<0, 0><<<H1 / 4, 256, 0, stream>>>(fv1, hf1,
      Wpf + 2 * 16384, bif + 2 * DH, Whf + 2 * 16384, bhf + 2 * DH,
      Wof + 2 * 4096, bof + 2 * DF, fvup2, dof, flag);
  finalize_even_kernel<0><<<(NV1 * DF + 255) / 256, 256, 0, stream>>>(
      fvup2, dof, nullptr, fv1, d_out, 450000, flag, NV1);
  hipMemsetAsync(fv1, 0, (size_t)NE1 * 3 * 4, stream);  // reuse fv1 as odd3
  flap_mlp<2, 0><<<H1 / 4, 256, 0, stream>>>(fvup2, hf1,
      Wpf + 3 * 16384, bif + 3 * DH, Whf + 3 * 16384, bhf + 3 * DH,
      Wof + 3 * 4096, bof + 3 * DF, fv1, nullptr, flag);
  finalize_odd_pos_kernel<<<(NE1 * 3 + 255) / 256, 256, 0, stream>>>(
      fv1, hf1, fvup2, d_out, 450000, flag, NE1, NV1);
}

// Round 5
// 931.439 us; speedup vs baseline: 11.5948x; 11.5948x over previous
//
#include <hip/hip_runtime.h>

#define NV0 30000
#define NE0 90000
#define H0 (2*NE0)      // 180000
#define NV1 (NV0+NE0)   // 120000
#define NE1 (3*NE0)     // 270000
#define H1 (2*NE1)      // 540000
#define DF 32
#define DH 128

typedef unsigned short bf16_t;
typedef unsigned int u32;
typedef __attribute__((ext_vector_type(8))) short short8;
typedef __attribute__((ext_vector_type(4))) float f32x4;

__device__ __forceinline__ float bf2f(bf16_t b) { return __uint_as_float(((u32)b) << 16); }
__device__ __forceinline__ bf16_t f2bf(float f) {
  u32 u = __float_as_uint(f);
  return (bf16_t)((u + 0x7fffu + ((u >> 16) & 1u)) >> 16);
}
__device__ __forceinline__ u32 pack2bf(float a, float b) {
  return (u32)f2bf(a) | ((u32)f2bf(b) << 16);
}
__device__ __forceinline__ float load_f(const void* p, long i, int isf32) {
  return isf32 ? ((const float*)p)[i] : bf2f(((const bf16_t*)p)[i]);
}
__device__ __forceinline__ void store_out(void* p, long i, float v, int isf32) {
  if (isf32) ((float*)p)[i] = v;
  else ((bf16_t*)p)[i] = f2bf(v);
}

struct F3 { float x, y, z; };
__device__ __forceinline__ F3 mkf3(float x, float y, float z){ F3 r; r.x=x; r.y=y; r.z=z; return r; }
__device__ __forceinline__ F3 f3sub(F3 a, F3 b){ return mkf3(a.x-b.x, a.y-b.y, a.z-b.z); }
__device__ __forceinline__ F3 f3add(F3 a, F3 b){ return mkf3(a.x+b.x, a.y+b.y, a.z+b.z); }
__device__ __forceinline__ float f3dot(F3 a, F3 b){ return a.x*b.x + a.y*b.y + a.z*b.z; }
__device__ __forceinline__ F3 f3crs(F3 a, F3 b){
  return mkf3(a.y*b.z - a.z*b.y, a.z*b.x - a.x*b.z, a.x*b.y - a.y*b.x);
}
__device__ __forceinline__ F3 f3nrm(F3 a){
  float r = rsqrtf(f3dot(a,a));
  return mkf3(a.x*r, a.y*r, a.z*r);
}

// ---- dtype detection
__global__ __launch_bounds__(256) void detect_kernel(const u32* __restrict__ fvw,
                                                     int* __restrict__ flag) {
  __shared__ int cnt;
  if (threadIdx.x == 0) cnt = 0;
  __syncthreads();
  int c = 0;
  #pragma unroll
  for (int j = 0; j < 2; ++j) {
    u32 w = fvw[threadIdx.x * 2 + j];
    u32 e = (w >> 7) & 0xffu;
    if (e > 140u) c++;
  }
  if (c) atomicAdd(&cnt, c);
  __syncthreads();
  if (threadIdx.x == 0) *flag = (cnt > 8) ? 1 : 0;
}

// biases: flagged dtype -> fp32
__global__ __launch_bounds__(256) void cvt_weights_kernel(const void* __restrict__ src,
                                                          float* __restrict__ dst, int n,
                                                          const int* __restrict__ flag) {
  int t = blockIdx.x * 256 + threadIdx.x;
  if (t >= n) return;
  dst[t] = load_f(src, t, *flag);
}

// Transposed bf16 weights for MFMA B-operand (layout [subnet][n][k], k contiguous).
__global__ __launch_bounds__(256) void pt_win_kernel(const void* __restrict__ W_in,
                                                     bf16_t* __restrict__ dst,
                                                     const int* __restrict__ flag) {
  int t = blockIdx.x * 256 + threadIdx.x;
  if (t >= 4 * DH * DH) return;
  int s = t >> 14, n = (t >> 7) & 127, k = t & 127;
  float v = (k >= 3) ? load_f(W_in, (long)s * (125 * DH) + (k - 3) * DH + n, *flag) : 0.f;
  dst[t] = f2bf(v);
}
__global__ __launch_bounds__(256) void pt_wh_kernel(const void* __restrict__ W_h,
                                                    bf16_t* __restrict__ dst,
                                                    const int* __restrict__ flag) {
  int t = blockIdx.x * 256 + threadIdx.x;
  if (t >= 4 * DH * DH) return;
  int s = t >> 14, n = (t >> 7) & 127, k = t & 127;
  dst[t] = f2bf(load_f(W_h, (long)s * (DH * DH) + k * DH + n, *flag));
}
__global__ __launch_bounds__(256) void pt_wo_kernel(const void* __restrict__ W_out,
                                                    bf16_t* __restrict__ dst,
                                                    const int* __restrict__ flag) {
  int t = blockIdx.x * 256 + threadIdx.x;
  if (t >= 4 * 32 * DH) return;
  int s = t >> 12, n = (t >> 7) & 31, k = t & 127;
  dst[t] = f2bf(load_f(W_out, (long)s * (DH * 32) + k * 32 + n, *flag));
}

// output 0: exact passthrough of fv positions
__global__ __launch_bounds__(256) void cvt_out0_kernel(const void* __restrict__ fv,
                                                       void* __restrict__ out,
                                                       const int* __restrict__ flag) {
  int t = blockIdx.x * 256 + threadIdx.x;
  if (t >= NV0 * 3) return;
  int v = t / 3, c = t - v * 3;
  if (*flag) ((float*)out)[t] = ((const float*)fv)[v * DF + c];
  else ((bf16_t*)out)[t] = ((const bf16_t*)fv)[v * DF + c];
}

#define XST 136   // LDS row stride (bf16 elems): 272B ≡ 68 dw ≡ 4 mod 32 -> mild conflicts only
#define YST 34    // Y fp32 row stride (dwords)

__device__ __forceinline__ f32x4 mfma16(short8 a, short8 b, f32x4 c) {
  return __builtin_amdgcn_mfma_f32_16x16x32_bf16(a, b, c, 0, 0, 0);
}

// Fused per-pass kernel: gather + flap-normalize + 3-layer MFMA MLP + local2global + pool.
template<int MODE, int RAW>
__global__ __launch_bounds__(256) void mlp3_kernel(
    const void* __restrict__ fvin, const int* __restrict__ hfIdx, int nH,
    const bf16_t* __restrict__ Wt1, const bf16_t* __restrict__ Wt2,
    const bf16_t* __restrict__ Wt3,
    const float* __restrict__ b1, const float* __restrict__ b2,
    const float* __restrict__ b3,
    float* __restrict__ outp, float* __restrict__ dofp,
    const int* __restrict__ flag)
{
  __shared__ __align__(16) short Xl[64 * XST];   // X tile; later H2; later Y (fp32)
  __shared__ __align__(16) short Hl[64 * XST];   // H1 tile
  __shared__ __align__(16) short Wl[64 * XST];   // W half-tile (64 rows x 128 k)
  __shared__ int   idxl[64 * 4];
  __shared__ float LFl[64 * 9];
  __shared__ float posl[64 * 12];

  const int t = threadIdx.x;
  const int lane = t & 63;
  const int wv = t >> 6;
  const int m0 = wv * 16;
  const int arow = lane & 15;
  const int koff = (lane >> 4) * 8;
  const int rrow = (lane >> 4) * 4;
  const long h0 = (long)blockIdx.x * 64;
  const int isf32 = RAW ? *flag : 1;

  // ---- phase 0: flap indices (clamped for pad rows)
  if (t < 64) {
    long h = h0 + t;
    int4 iv = (h < nH) ? ((const int4*)hfIdx)[h] : make_int4(0, 0, 0, 0);
    idxl[t * 4 + 0] = iv.x; idxl[t * 4 + 1] = iv.y;
    idxl[t * 4 + 2] = iv.z; idxl[t * 4 + 3] = iv.w;
  }
  __syncthreads();

  // ---- phase 1: gather (thread t -> flap m=t>>2, vertex v=t&3, 32 channels)
  {
    int m = t >> 2, v = t & 3;
    int vid = idxl[m * 4 + v];
    u32* xrow = (u32*)(Xl + m * XST + v * 32);
    if (RAW && !isf32) {
      const uint4* src = (const uint4*)((const bf16_t*)fvin + (size_t)vid * DF);
      #pragma unroll
      for (int j = 0; j < 4; ++j) {
        uint4 x = src[j];
        xrow[j * 4 + 0] = x.x; xrow[j * 4 + 1] = x.y;
        xrow[j * 4 + 2] = x.z; xrow[j * 4 + 3] = x.w;
        if (j == 0) {
          posl[m * 12 + v * 3 + 0] = bf2f((bf16_t)(x.x & 0xffff));
          posl[m * 12 + v * 3 + 1] = bf2f((bf16_t)(x.x >> 16));
          posl[m * 12 + v * 3 + 2] = bf2f((bf16_t)(x.y & 0xffff));
        }
      }
    } else {
      const float4* src = (const float4*)((const float*)fvin + (size_t)vid * DF);
      #pragma unroll
      for (int j = 0; j < 8; ++j) {
        float4 x = src[j];
        xrow[j * 2 + 0] = pack2bf(x.x, x.y);
        xrow[j * 2 + 1] = pack2bf(x.z, x.w);
        if (j == 0) {
          posl[m * 12 + v * 3 + 0] = x.x;
          posl[m * 12 + v * 3 + 1] = x.y;
          posl[m * 12 + v * 3 + 2] = x.z;
        }
      }
    }
  }
  __syncthreads();

  // ---- phase 2: local frame per flap (threads 0..63), fp32 positions
  if (t < 64) {
    const float* P = posl + t * 12;
    F3 p0 = mkf3(P[0], P[1], P[2]);
    F3 p1 = mkf3(P[3], P[4], P[5]);
    F3 p2 = mkf3(P[6], P[7], P[8]);
    F3 p3 = mkf3(P[9], P[10], P[11]);
    F3 e1  = f3sub(p1, p0);
    F3 B1  = f3nrm(e1);
    F3 fn0 = f3nrm(f3crs(e1, f3sub(p2, p0)));
    F3 fn1 = f3nrm(f3crs(f3sub(p0, p1), f3sub(p3, p1)));
    F3 B3  = f3nrm(f3add(fn0, fn1));
    F3 B2  = f3crs(B3, B1);
    F3 d2 = f3sub(p2, p0), d3 = f3sub(p3, p0);
    short* xr = Xl + t * XST;
    xr[32] = f2bf(f3dot(e1, B1)); xr[33] = f2bf(f3dot(e1, B2)); xr[34] = f2bf(f3dot(e1, B3));
    xr[64] = f2bf(f3dot(d2, B1)); xr[65] = f2bf(f3dot(d2, B2)); xr[66] = f2bf(f3dot(d2, B3));
    xr[96] = f2bf(f3dot(d3, B1)); xr[97] = f2bf(f3dot(d3, B2)); xr[98] = f2bf(f3dot(d3, B3));
    // v0 pos channels (k 0..2) hit zero rows of Wt1 -> no need to clear
    float* lf = LFl + t * 9;
    lf[0] = B1.x; lf[1] = B1.y; lf[2] = B1.z;
    lf[3] = B2.x; lf[4] = B2.y; lf[5] = B2.z;
    lf[6] = B3.x; lf[7] = B3.y; lf[8] = B3.z;
  }
  __syncthreads();

  short8 af[4];
  // ======== LAYER 1: Hl = relu(Xl @ W1 + b1) ========
  #pragma unroll
  for (int kq = 0; kq < 4; ++kq)
    af[kq] = *(const short8*)(Xl + (m0 + arow) * XST + kq * 32 + koff);
  #pragma unroll
  for (int half = 0; half < 2; ++half) {
    // stage 64 rows x 128 k of Wt1 (64 dwords per row)
    for (int i = t; i < 64 * 64; i += 256)
      ((u32*)(Wl + (i >> 6) * XST))[i & 63] = ((const u32*)Wt1)[(half * 64 + (i >> 6)) * 64 + (i & 63)];
    __syncthreads();
    #pragma unroll
    for (int ntl = 0; ntl < 4; ntl += 2) {
      f32x4 a0 = {0.f,0.f,0.f,0.f}, a1 = {0.f,0.f,0.f,0.f};
      #pragma unroll
      for (int kq = 0; kq < 4; ++kq) {
        short8 w0 = *(const short8*)(Wl + (ntl * 16 + arow) * XST + kq * 32 + koff);
        short8 w1 = *(const short8*)(Wl + ((ntl + 1) * 16 + arow) * XST + kq * 32 + koff);
        a0 = mfma16(af[kq], w0, a0);
        a1 = mfma16(af[kq], w1, a1);
      }
      int c0 = half * 64 + ntl * 16 + arow, c1 = c0 + 16;
      float bb0 = b1[c0], bb1 = b1[c1];
      #pragma unroll
      for (int r = 0; r < 4; ++r) {
        int rm = m0 + rrow + r;
        Hl[rm * XST + c0] = (short)f2bf(fmaxf(a0[r] + bb0, 0.f));
        Hl[rm * XST + c1] = (short)f2bf(fmaxf(a1[r] + bb1, 0.f));
      }
    }
    __syncthreads();
  }

  // ======== LAYER 2: Xl = relu(Hl @ W2 + b2) ========
  #pragma unroll
  for (int kq = 0; kq < 4; ++kq)
    af[kq] = *(const short8*)(Hl + (m0 + arow) * XST + kq * 32 + koff);
  #pragma unroll
  for (int half = 0; half < 2; ++half) {
    for (int i = t; i < 64 * 64; i += 256)
      ((u32*)(Wl + (i >> 6) * XST))[i & 63] = ((const u32*)Wt2)[(half * 64 + (i >> 6)) * 64 + (i & 63)];
    __syncthreads();
    #pragma unroll
    for (int ntl = 0; ntl < 4; ntl += 2) {
      f32x4 a0 = {0.f,0.f,0.f,0.f}, a1 = {0.f,0.f,0.f,0.f};
      #pragma unroll
      for (int kq = 0; kq < 4; ++kq) {
        short8 w0 = *(const short8*)(Wl + (ntl * 16 + arow) * XST + kq * 32 + koff);
        short8 w1 = *(const short8*)(Wl + ((ntl + 1) * 16 + arow) * XST + kq * 32 + koff);
        a0 = mfma16(af[kq], w0, a0);
        a1 = mfma16(af[kq], w1, a1);
      }
      int c0 = half * 64 + ntl * 16 + arow, c1 = c0 + 16;
      float bb0 = b2[c0], bb1 = b2[c1];
      #pragma unroll
      for (int r = 0; r < 4; ++r) {
        int rm = m0 + rrow + r;
        Xl[rm * XST + c0] = (short)f2bf(fmaxf(a0[r] + bb0, 0.f));
        Xl[rm * XST + c1] = (short)f2bf(fmaxf(a1[r] + bb1, 0.f));
      }
    }
    __syncthreads();
  }

  // ======== LAYER 3: Y = H2 @ W3 + b3 (N=32, no relu); Y -> fp32 over Xl ========
  #pragma unroll
  for (int kq = 0; kq < 4; ++kq)
    af[kq] = *(const short8*)(Xl + (m0 + arow) * XST + kq * 32 + koff);
  __syncthreads();   // all af loaded before Yf writes clobber Xl
  for (int i = t; i < 32 * 64; i += 256)
    ((u32*)(Wl + (i >> 6) * XST))[i & 63] = ((const u32*)Wt3)[(i >> 6) * 64 + (i & 63)];
  __syncthreads();
  float* Yf = (float*)Xl;
  {
    f32x4 a0 = {0.f,0.f,0.f,0.f}, a1 = {0.f,0.f,0.f,0.f};
    #pragma unroll
    for (int kq = 0; kq < 4; ++kq) {
      short8 w0 = *(const short8*)(Wl + (arow) * XST + kq * 32 + koff);
      short8 w1 = *(const short8*)(Wl + (16 + arow) * XST + kq * 32 + koff);
      a0 = mfma16(af[kq], w0, a0);
      a1 = mfma16(af[kq], w1, a1);
    }
    float bb0 = b3[arow], bb1 = b3[16 + arow];
    #pragma unroll
    for (int r = 0; r < 4; ++r) {
      int rm = m0 + rrow + r;
      Yf[rm * YST + arow] = a0[r] + bb0;
      Yf[rm * YST + 16 + arow] = a1[r] + bb1;
    }
  }
  __syncthreads();

  // ======== epilogue: local2global + pool (each wave: its own 16 rows) ========
  #pragma unroll
  for (int i = 0; i < 8; ++i) {
    int row = m0 + i * 2 + (lane >> 5);
    long h = h0 + row;
    if (h < nH) {
      int ch = lane & 31;
      float val = Yf[row * YST + ch];
      if (ch < 3) {
        float y0 = Yf[row * YST + 0], y1 = Yf[row * YST + 1], y2 = Yf[row * YST + 2];
        val = y0 * LFl[row * 9 + ch] + y1 * LFl[row * 9 + 3 + ch] + y2 * LFl[row * 9 + 6 + ch];
      }
      if (MODE == 0) {
        atomicAdd(&outp[(size_t)idxl[row * 4] * DF + ch], val);
        if (ch == 0) atomicAdd(&dofp[idxl[row * 4]], 1.f);
      } else if (MODE == 1) {
        atomicAdd(&outp[(size_t)(h >> 1) * DF + ch], 0.5f * val);
      } else {
        if (ch < 3) atomicAdd(&outp[(size_t)(h >> 1) * 3 + ch], 0.5f * val);
      }
    }
  }
}

// ---- finalize kernels ----
template<int RAW>
__global__ __launch_bounds__(256) void finalize_even_kernel(
    float* buf, const float* __restrict__ dof,
    const void* __restrict__ prevraw, const float* __restrict__ prevf,
    void* __restrict__ out, int outbase, const int* __restrict__ flag, int nV) {
  int t = blockIdx.x * 256 + threadIdx.x;
  if (t >= nV * DF) return;
  int v = t >> 5, c = t & 31;
  float val = buf[t] / fmaxf(dof[v], 1.0f);
  if (c < 3) {
    float pp = RAW ? load_f(prevraw, (long)v * DF + c, *flag) : prevf[(long)v * DF + c];
    val += pp;
    store_out(out, (long)outbase + (long)v * 3 + c, val, *flag);
  }
  buf[t] = val;
}

__global__ __launch_bounds__(256) void finalize_odd_full_kernel(
    float* oddbuf, const int* __restrict__ hfIdx,
    const float* fveven, void* __restrict__ out, int outbase,
    const int* __restrict__ flag, int nE, int nVeven) {
  int t = blockIdx.x * 256 + threadIdx.x;
  if (t >= nE * DF) return;
  int e = t >> 5, c = t & 31;
  float val = oddbuf[t];
  if (c < 3) {
    int a0 = hfIdx[(size_t)(2 * e) * 4 + 0];
    int a1 = hfIdx[(size_t)(2 * e) * 4 + 1];
    int b0 = hfIdx[(size_t)(2 * e + 1) * 4 + 0];
    int b1 = hfIdx[(size_t)(2 * e + 1) * 4 + 1];
    val += 0.25f * (fveven[(size_t)a0 * DF + c] + fveven[(size_t)a1 * DF + c] +
                    fveven[(size_t)b0 * DF + c] + fveven[(size_t)b1 * DF + c]);
    store_out(out, (long)outbase + (long)(nVeven + e) * 3 + c, val, *flag);
  }
  oddbuf[t] = val;
}

__global__ __launch_bounds__(256) void finalize_odd_pos_kernel(
    const float* __restrict__ odd3, const int* __restrict__ hfIdx,
    const float* __restrict__ fveven, void* __restrict__ out, int outbase,
    const int* __restrict__ flag, int nE, int nVeven) {
  int t = blockIdx.x * 256 + threadIdx.x;
  if (t >= nE * 3) return;
  int e = t / 3, c = t - e * 3;
  int a0 = hfIdx[(size_t)(2 * e) * 4 + 0];
  int a1 = hfIdx[(size_t)(2 * e) * 4 + 1];
  int b0 = hfIdx[(size_t)(2 * e + 1) * 4 + 0];
  int b1 = hfIdx[(size_t)(2 * e + 1) * 4 + 1];
  float val = odd3[t] + 0.25f * (fveven[(size_t)a0 * DF + c] + fveven[(size_t)a1 * DF + c] +
                                 fveven[(size_t)b0 * DF + c] + fveven[(size_t)b1 * DF + c]);
  store_out(out, (long)outbase + (long)(nVeven + e) * 3 + c, val, *flag);
}

extern "C" void kernel_launch(void* const* d_in, const int* in_sizes, int n_in,
                              void* d_out, int out_size, void* d_ws, size_t ws_size,
                              hipStream_t stream) {
  const void* fv    = d_in[0];
  const void* W_in  = d_in[1];
  const void* b_in  = d_in[2];
  const void* W_h   = d_in[3];
  const void* b_h   = d_in[4];
  const void* W_out = d_in[5];
  const void* b_out = d_in[6];
  const int* hf0 = (const int*)d_in[7];
  const int* hf1 = (const int*)d_in[8];
  (void)in_sizes; (void)n_in; (void)out_size;

  // workspace (~29.8 MiB)
  float* fv1   = (float*)d_ws;            // 3,840,000 (120000x32)
  float* fvup2 = fv1   + 3840000;         // 3,840,000
  float* dof   = fvup2 + 3840000;         // 120,000
  float* bif   = dof   + 120000;          // 512
  float* bhf   = bif   + 512;             // 512
  float* bof   = bhf   + 512;             // 128
  int*   flag  = (int*)(bof + 128);       // 4 ints (1 used)
  bf16_t* Wti  = (bf16_t*)(flag + 4);     // 4x128x128
  bf16_t* Wth  = Wti + 65536;             // 4x128x128
  bf16_t* Wto  = Wth + 65536;             // 4x32x128
  const size_t needed = ((size_t)3840000 * 2 + 120000 + 512 * 2 + 128 + 4) * 4
                      + (65536 * 2 + 16384) * 2;
  if (ws_size < needed) return;

  float* odd_acc0 = fv1 + (size_t)NV0 * DF;  // level-0 odd region (90000x32)

  // ---- dtype detect + weight staging
  detect_kernel<<<1, 256, 0, stream>>>((const u32*)fv, flag);
  pt_win_kernel<<<256, 256, 0, stream>>>(W_in, Wti, flag);
  pt_wh_kernel<<<256, 256, 0, stream>>>(W_h, Wth, flag);
  pt_wo_kernel<<<64, 256, 0, stream>>>(W_out, Wto, flag);
  cvt_weights_kernel<<<2, 256, 0, stream>>>(b_in, bif, 512, flag);
  cvt_weights_kernel<<<2, 256, 0, stream>>>(b_h, bhf, 512, flag);
  cvt_weights_kernel<<<1, 256, 0, stream>>>(b_out, bof, 128, flag);
  cvt_out0_kernel<<<(NV0 * 3 + 255) / 256, 256, 0, stream>>>(fv, d_out, flag);

  const int G0 = (H0 + 63) / 64, G1 = (H1 + 63) / 64;

  // ================= level 0 =================
  hipMemsetAsync(fv1, 0, (size_t)NV0 * DF * 4, stream);
  hipMemsetAsync(dof, 0, (size_t)NV0 * 4, stream);
  mlp3_kernel<0, 1><<<G0, 256, 0, stream>>>(fv, hf0, H0,
      Wti + 0 * 16384, Wth + 0 * 16384, Wto + 0 * 4096,
      bif + 0 * DH, bhf + 0 * DH, bof + 0 * DF, fv1, dof, flag);
  finalize_even_kernel<1><<<(NV0 * DF + 255) / 256, 256, 0, stream>>>(
      fv1, dof, fv, nullptr, d_out, 90000, flag, NV0);
  hipMemsetAsync(odd_acc0, 0, (size_t)NE0 * DF * 4, stream);
  mlp3_kernel<1, 0><<<G0, 256, 0, stream>>>(fv1, hf0, H0,
      Wti + 1 * 16384, Wth + 1 * 16384, Wto + 1 * 4096,
      bif + 1 * DH, bhf + 1 * DH, bof + 1 * DF, odd_acc0, nullptr, flag);
  finalize_odd_full_kernel<<<(NE0 * DF + 255) / 256, 256, 0, stream>>>(
      odd_acc0, hf0, fv1, d_out, 90000, flag, NE0, NV0);

  // ================= level 1 =================
  hipMemsetAsync(fvup2, 0, (size_t)NV1 * DF * 4, stream);
  hipMemsetAsync(dof, 0, (size_t)NV1 * 4, stream);
  mlp3_kernel<0, 0><<<G1, 256, 0, stream>>>(fv1, hf1, H1,
      Wti + 2 * 16384, Wth + 2 * 16384, Wto + 2 * 4096,
      bif + 2 * DH, bhf + 2 * DH, bof + 2 * DF, fvup2, dof, flag);
  finalize_even_kernel<0><<<(NV1 * DF + 255) / 256, 256, 0, stream>>>(
      fvup2, dof, nullptr, fv1, d_out, 450000, flag, NV1);
  hipMemsetAsync(fv1, 0, (size_t)NE1 * 3 * 4, stream);  // reuse fv1 as odd3
  mlp3_kernel<2, 0><<<G1, 256, 0, stream>>>(fvup2, hf1, H1,
      Wti + 3 * 16384, Wth + 3 * 16384, Wto + 3 * 4096,
      bif + 3 * DH, bhf + 3 * DH, bof + 3 * DF, fv1, nullptr, flag);
  finalize_odd_pos_kernel<<<(NE1 * 3 + 255) / 256, 256, 0, stream>>>(
      fv1, hf1, fvup2, d_out, 450000, flag, NE1, NV1);
}